// Round 1
// baseline (86.160 us; speedup 1.0000x reference)
//
#include <hip/hip_runtime.h>
#include <math.h>

#define N 4096
#define FEPS 1e-7f
#define BLK 256
#define JT 64           // grid = 16*64 = 1024 blocks = 4/CU = 4 waves/SIMD
#define CH (N / JT)     // 64 j's per block
#define LSTRIDE 12
#define N6 (N * 6)

// d_ws layout: part[jt][i*6+k] : JT*N*6 floats = 6.29 MB,
//              feat[i*12+k]    : N*12 floats  = 196 KB (after part).

// Per-box record (12 floats): 0:conf 1:x1 2:y1 3:x2 4:y2 5:(x1+x2)/2
// 6:(y1+y2)/2 7:w 8:h 9:area+eps/2 10:(2/pi)*atan(w/(h+eps)) 11:conf*sqrt(log2e)
// Folds: K=4/pi^2 into atan, rho2's /4 into half-coords, union-eps split
// across the two records, log2(e) for v_exp_f32 (2^x) into conf.
__device__ __forceinline__ void box_record(const float* __restrict__ x, int i, float* rec) {
    float cf = x[i * 5 + 0], x1 = x[i * 5 + 1], y1 = x[i * 5 + 2];
    float x2 = x[i * 5 + 3], y2 = x[i * 5 + 4];
    float w = x2 - x1, h = y2 - y1;
    rec[0] = cf; rec[1] = x1; rec[2] = y1; rec[3] = x2; rec[4] = y2;
    rec[5] = (x1 + x2) * 0.5f; rec[6] = (y1 + y2) * 0.5f; rec[7] = w; rec[8] = h;
    rec[9] = w * h + 0.5f * FEPS;
    rec[10] = 0.6366197723675814f * atanf(w / (h + FEPS));
    rec[11] = cf * 1.2011224087864498f;
}

// Tiny precompute pass: 12-float record per box -> global feature table.
// Stride 48 B is 16-aligned, so 3x float4 stores.
__global__ void feat_kernel(const float* __restrict__ x, float* __restrict__ feat) {
    int i = blockIdx.x * blockDim.x + threadIdx.x;
    if (i >= N) return;
    float rec[12];
    box_record(x, i, rec);
    float4* dst = (float4*)(feat + (size_t)i * LSTRIDE);
    dst[0] = make_float4(rec[0], rec[1], rec[2], rec[3]);
    dst[1] = make_float4(rec[4], rec[5], rec[6], rec[7]);
    dst[2] = make_float4(rec[8], rec[9], rec[10], rec[11]);
}

// Row-per-lane, SGPR-broadcast j-loop. Block (gb, jt): lane owns row
// i = gb*256+tid; j-chunk [jt*64, jt*64+64).
//
// r0->r1 change (theory: LDS-issue-bound): the j-record address depends only
// on blockIdx/loop counter -> wave-uniform -> compiler emits s_load_dwordx4
// into SGPRs (SMEM pipe). This removes the 12 broadcast ds_reads/iter that
// serialized on the single per-CU LDS pipe (~30 us/CU at 16 waves x 64 iter).
// Every inner VALU op reads at most ONE j-scalar (SGPR) + row VGPRs — legal
// operand mix, checked per instruction. No LDS, no __syncthreads.
//
// Also fused: rcp(c2) & rcp(den) -> single rcp(c2*den):
//   rho2/c2 + v^2/den == (rho2*den + v^2*c2) / (c2*den).   4 trans -> 3.
// Diagonal (iou=1, v=0): num = 0*eps = 0 -> ciou = iou, same as before.
// iou clamped to 1.0: fast-rcp 1-ulp overshoot otherwise zeroes den on
// diagonal pairs -> 0*inf = NaN (measured in the earlier session).
// NOTE (prior session, measured): no 2nd __launch_bounds__ arg — (256,4)
// forced VGPR=64 and spilled ~90 MB/dispatch to scratch.
__global__ __launch_bounds__(BLK) void ciou_attn_kernel(
        const float* __restrict__ feat,
        float* __restrict__ part) {
    const int tid = threadIdx.x;
    const int gb = blockIdx.x / JT;
    const int jt = blockIdx.x % JT;
    const int i = gb * BLK + tid;

    // Per-lane row record: 3x coalesced float4 loads (48 B stride, aligned).
    const float4* rp = (const float4*)(feat + (size_t)i * LSTRIDE);
    float4 r0 = rp[0], r1 = rp[1], r2 = rp[2];
    const float rx1 = r0.y, ry1 = r0.z, rx2 = r0.w, ry2 = r1.x;
    const float rhx = r1.y, rhy = r1.z, rw = r1.w, rh = r2.x;
    const float rareps = r2.y, rat = r2.z, rcf2 = r2.w;

    float sum = 0.f, a0 = 0.f, a1 = 0.f, a2 = 0.f, a3 = 0.f, a4 = 0.f;
    const float ONEP = 1.f + FEPS;
    const float* __restrict__ fj = feat + (size_t)jt * CH * LSTRIDE;

#pragma unroll 4
    for (int jj = 0; jj < CH; jj++) {
        const float* f = fj + jj * LSTRIDE;  // uniform address -> s_load
        float jcf = f[0], jx1 = f[1], jy1 = f[2], jx2 = f[3], jy2 = f[4];
        float jhx = f[5], jhy = f[6], jw = f[7], jh = f[8];
        float jareps = f[9], jat = f[10], jcf2 = f[11];

        float iwr = fminf(rx2, jx2) - fmaxf(rx1, jx1);
        float ihr = fminf(ry2, jy2) - fmaxf(ry1, jy1);
        float iw = fmaxf(iwr, 0.f);
        float ih = fmaxf(ihr, 0.f);
        float inter = iw * ih;
        float uni = (rareps + jareps) - inter;
        float iou = fminf(inter * __builtin_amdgcn_rcpf(uni), 1.0f);
        float cw = (rw + jw) - iwr;              // enclosing box identity
        float chh = (rh + jh) - ihr;
        float c2 = fmaf(cw, cw, fmaf(chh, chh, FEPS));
        float dx = jhx - rhx;
        float dy = jhy - rhy;
        float rho2 = fmaf(dx, dx, dy * dy);      // /4 pre-folded
        float da = jat - rat;                    // K pre-folded
        float v = da * da;
        float den = (v - iou) + ONEP;
        float num = fmaf(v * v, c2, rho2 * den); // rho2/c2 + v^2/den, fused
        float ciou = fmaf(-num, __builtin_amdgcn_rcpf(c2 * den), iou);
        float e = __builtin_amdgcn_exp2f(ciou * (rcf2 * jcf2));  // e^s
        sum += e;
        a0 = fmaf(e, jcf, a0);
        a1 = fmaf(e, jx1, a1);
        a2 = fmaf(e, jy1, a2);
        a3 = fmaf(e, jx2, a3);
        a4 = fmaf(e, jy2, a4);
    }

    float* p = part + (size_t)jt * N6 + (size_t)i * 6;
    p[0] = sum; p[1] = a0; p[2] = a1; p[3] = a2; p[4] = a3; p[5] = a4;
}

// One thread per output element (i,c): sum JT partials, softmax-divide, sigmoid.
__global__ void epilogue_kernel(const float* __restrict__ x,
                                const float* __restrict__ gamma,
                                const float* __restrict__ part,
                                float* __restrict__ out) {
    int idx = blockIdx.x * blockDim.x + threadIdx.x;
    if (idx >= N * 5) return;
    int i = idx / 5, c = idx % 5;
    float se = 0.f, a = 0.f;
    const float* p = part + (size_t)i * 6;
#pragma unroll 8
    for (int jt = 0; jt < JT; jt++) {
        se += p[jt * (size_t)N6 + 0];
        a  += p[jt * (size_t)N6 + 1 + c];
    }
    float xp = x[idx] * gamma[0] + a / se;
    out[idx] = 1.f / (1.f + expf(-xp));
}

extern "C" void kernel_launch(void* const* d_in, const int* in_sizes, int n_in,
                              void* d_out, int out_size, void* d_ws, size_t ws_size,
                              hipStream_t stream) {
    const float* x = (const float*)d_in[0];
    const float* gamma = (const float*)d_in[1];
    float* out = (float*)d_out;
    float* part = (float*)d_ws;                        // JT*N*6 floats = 6.29 MB
    float* feat = part + (size_t)JT * N6;              // N*12 floats  = 196 KB

    feat_kernel<<<(N + BLK - 1) / BLK, BLK, 0, stream>>>(x, feat);
    ciou_attn_kernel<<<(N / BLK) * JT, BLK, 0, stream>>>(feat, part);
    epilogue_kernel<<<(N * 5 + 255) / 256, 256, 0, stream>>>(x, gamma, part, out);
}